// Round 4
// baseline (95.397 us; speedup 1.0000x reference)
//
#include <hip/hip_runtime.h>

// s = sum_{b,i,j} X[b,i] W[i,j] G[b,i/128,j/128]; out = s^2.
// Factor over j:  s = sum_{i,jb} Wsum[i,jb] * H[i,jb],
//   Wsum[i,jb] = sum_{c<128} W[i, jb*128+c]          (needs only W)
//   H[i,jb]    = sum_b X[b,i] * G[b, i/128, jb]      (needs only X,G)
//
// R10: R9 minus the LDS-G machinery. R9 post-mortem: the H path's 331k
// ds_read_b128 were concentrated on 144 CUs (~11us LDS-pipe serial) and
// X MLP was too shallow. Fix: G's inner-loop address is wave-uniform
// (b and ib have no lane term) -> readfirstlane'd base lets hipcc emit
// s_load_dwordx4 via the SCALAR cache (idle pipe; G is 2.65MB, L2-hot).
// No LDS, no stage, no __syncthreads in the H path; X unroll 8 for MLP.
// W path / Hp 24-slice layout / phases B,C identical to verified R9.
//   A: blocks 0..143   : partial-H (block=(ib,bchunk of 128), b-parity
//                        split across thread halves, G via SMEM broadcast)
//      blocks 144..2447: WsumT[jb][i] (3 float4-units/wave, shfl reduce)
//   B: 216 blocks: s += WsumT[T] * sum_sp Hp[sp*55296+T], block partials.
//   C: 1 block: reduce 216 partials, square.

#define B_DIM 1536
#define DI    1536
#define DO    4608
#define NI    12
#define NJ    36
#define GROW  (NI * NJ)          // 432 floats per G batch-row
#define HGRID (NJ * DI)          // 55296 floats per Hp slice
#define NSP   (NI * 2)           // 24 Hp slices: (bchunk, b-parity)
#define NHB   144                // H blocks: 12 ib x 12 bchunks
#define WUPW  3                  // Wsum units per wave
#define NWW   (27648 / WUPW)     // 9216 W waves
#define NWB   (NWW / 4)          // 2304 W blocks
#define NB_A  (NHB + NWB)        // 2448
#define NB_B  (HGRID / 256)      // 216

// ---- Kernel A: concurrent Wsum (W-stream) + partial-H (X,G-stream) ----
__global__ __launch_bounds__(256) void phaseA(const float* __restrict__ X,
                                              const float* __restrict__ W,
                                              const float* __restrict__ G,
                                              float* __restrict__ WsumT,
                                              float* __restrict__ Hp) {
    const int t    = threadIdx.x;
    const int w    = t >> 6;
    const int lane = t & 63;
    const int beta = blockIdx.x;

    if (beta < NHB) {
        // ---- H path: block = (ib, bchunk of 128). Thread halves take
        // opposite b-parities (bp wave-uniform -> scalar G addressing).
        const int ib = beta / NI;
        const int bc = beta - ib * NI;
        const int b0 = bc * 128;
        const int il = t & 127;                                  // i_local
        const int bp = __builtin_amdgcn_readfirstlane(t >> 7);   // b parity

        const float* xp = X + (size_t)(b0 + bp) * DI + ib * 128 + il;
        const float* gp = G + (size_t)(b0 + bp) * GROW + ib * NJ; // uniform

        float acc[NJ];
        #pragma unroll
        for (int k = 0; k < NJ; ++k) acc[k] = 0.f;

        #pragma unroll 8
        for (int bl = 0; bl < 64; ++bl) {
            float x = xp[(size_t)bl * 2 * DI];                   // 256B/wave
            const float4* g4 = (const float4*)(gp + (size_t)bl * 2 * GROW);
            #pragma unroll
            for (int k = 0; k < 9; ++k) {                        // s_load x4:
                float4 g = g4[k];                                // scalar pipe
                acc[4 * k + 0] = fmaf(x, g.x, acc[4 * k + 0]);
                acc[4 * k + 1] = fmaf(x, g.y, acc[4 * k + 1]);
                acc[4 * k + 2] = fmaf(x, g.z, acc[4 * k + 2]);
                acc[4 * k + 3] = fmaf(x, g.w, acc[4 * k + 3]);
            }
        }
        // Slice per (bchunk, parity): no write collision between t and t+128.
        float* hp = Hp + (size_t)(bc * 2 + bp) * HGRID + ib * 128 + il;
        #pragma unroll
        for (int k = 0; k < NJ; ++k) hp[(size_t)k * DI] = acc[k];
    } else {
        // ---- Wsum path: unit g covers row i, chunk p -> jb {2p, 2p+1}.
        const int wgW = (beta - NHB) * 4 + w;
        float4 v[WUPW];
        int ii[WUPW], pp[WUPW];
        #pragma unroll
        for (int q = 0; q < WUPW; ++q) {
            int g = wgW + q * NWW;
            ii[q] = g / 18;
            pp[q] = g - ii[q] * 18;
            v[q] = ((const float4*)(W + (size_t)ii[q] * DO + pp[q] * 256))[lane];
        }
        #pragma unroll
        for (int q = 0; q < WUPW; ++q) {
            float s1 = (v[q].x + v[q].y) + (v[q].z + v[q].w);
            #pragma unroll
            for (int off = 16; off > 0; off >>= 1) s1 += __shfl_xor(s1, off, 64);
            // lanes 0..31 hold jb=2p, lanes 32..63 hold jb=2p+1
            if (lane == 0)  WsumT[(size_t)(2 * pp[q])     * DI + ii[q]] = s1;
            if (lane == 32) WsumT[(size_t)(2 * pp[q] + 1) * DI + ii[q]] = s1;
        }
    }
}

// ---- Kernel B: dot of Wsum with (sum of 24 Hp slices); 216 partials ----
__global__ __launch_bounds__(256) void phaseB(const float* __restrict__ WsumT,
                                              const float* __restrict__ Hp,
                                              float* __restrict__ partials) {
    __shared__ float red[4];
    const int t = threadIdx.x;
    const size_t T = (size_t)blockIdx.x * 256 + t;   // < 55296, flat [jb][i]
    float h0 = 0.f, h1 = 0.f, h2 = 0.f, h3 = 0.f;
    #pragma unroll
    for (int sp = 0; sp < NSP; sp += 4) {            // 4 chains for ILP
        h0 += Hp[(size_t)(sp + 0) * HGRID + T];
        h1 += Hp[(size_t)(sp + 1) * HGRID + T];
        h2 += Hp[(size_t)(sp + 2) * HGRID + T];
        h3 += Hp[(size_t)(sp + 3) * HGRID + T];
    }
    float s = WsumT[T] * ((h0 + h1) + (h2 + h3));
    #pragma unroll
    for (int off = 1; off < 64; off <<= 1) s += __shfl_xor(s, off, 64);
    const int w = t >> 6, lane = t & 63;
    if (lane == 0) red[w] = s;
    __syncthreads();
    if (t == 0)
        partials[blockIdx.x] = (red[0] + red[1]) + (red[2] + red[3]);
}

// ---- Kernel C: final reduce + square (1 block) ----
__global__ __launch_bounds__(256) void phaseC(const float* __restrict__ partials,
                                              float* __restrict__ out) {
    __shared__ float red[4];
    const int t = threadIdx.x;
    float s = (t < NB_B) ? partials[t] : 0.f;
    #pragma unroll
    for (int off = 1; off < 64; off <<= 1) s += __shfl_xor(s, off, 64);
    const int w = t >> 6, lane = t & 63;
    if (lane == 0) red[w] = s;
    __syncthreads();
    if (t == 0) {
        float tot = (red[0] + red[1]) + (red[2] + red[3]);
        out[0] = tot * tot;
    }
}

extern "C" void kernel_launch(void* const* d_in, const int* in_sizes, int n_in,
                              void* d_out, int out_size, void* d_ws, size_t ws_size,
                              hipStream_t stream) {
    const float* X = (const float*)d_in[0];  // [1536,1536]
    const float* W = (const float*)d_in[1];  // [1536,4608]
    const float* G = (const float*)d_in[2];  // [1536,12,36]
    float* out = (float*)d_out;

    float* WsumT    = (float*)d_ws;                  // [36][1536]
    float* Hp       = WsumT + HGRID;                 // [24][36][1536]
    float* partials = Hp + (size_t)NSP * HGRID;      // 216 floats

    phaseA<<<NB_A, 256, 0, stream>>>(X, W, G, WsumT, Hp);
    phaseB<<<NB_B, 256, 0, stream>>>(WsumT, Hp, partials);
    phaseC<<<1, 256, 0, stream>>>(partials, out);
}

// Round 5
// 90.605 us; speedup vs baseline: 1.0529x; 1.0529x over previous
//
#include <hip/hip_runtime.h>

// s = sum_{b,i,j} X[b,i] W[i,j] G[b,i/128,j/128]; out = s^2.
// Factor over j:  s = sum_{i,jb} Wsum[i,jb] * H[i,jb],
//   Wsum[i,jb] = sum_{c<128} W[i, jb*128+c]
//   H[i,jb]    = sum_b X[b,i] * G[b, i/128, jb]
// K1: WsumT[jb][i] (TRANSPOSED so k2's per-lane row read is coalesced).
// K2: lane<->i. G staged once per block into LDS via coalesced vector
//     loads; inner loop uses uniform-address LDS broadcasts (ds_read_b128,
//     same-address = conflict-free); Wsum read via WsumT coalesced.
//     No atomics (R4: cross-XCD ping-pong ~19 ns/RMW).
// K3: 1-block finish: reduce 1152 partials, square.
//
// R11 = exact revert to the verified R0 kernel (89.0 us). Post-mortems:
//  - R7 coop fusion: grid.sync+threadfence across 8 XCDs cost ~250 us.
//  - R9/R10 concurrent producers: H work concentrated on 144 CUs -> 11-13us
//    LDS/SMEM serial tail (total broadcast-inst count is distribution-
//    invariant; R0's 1152 blocks spread it over all 256 CUs) + 5.3 MB Hp
//    round-trip. Scalar-G repeats prior session's R6 trap (s_load chains
//    need ~288 SGPRs to pipeline -> serialize at cold latency).
// Budget: harness-fixed ~70-77us (256MiB poison fill ~44us + restores);
// kernels ~12us of which 4.6us is the compulsory 28.3MB W stream. All
// remaining structural levers have EV <= 1-2us at +-3us noise.

#define B_DIM 1536
#define DI    1536
#define DO    4608
#define NI    12
#define NJ    36
#define GROW  (NI * NJ)            // 432 floats per G batch-row
#define BPW   8                    // b's per wave in kernel 2
#define K2_WAVES  (24 * (B_DIM / BPW))   // 24 i-blocks x 192 b-ranges = 4608
#define K2_BLOCKS (K2_WAVES / 4)         // 1152

// ---- Kernel 1: WsumT[jb][i]; wave handles (i, jb-pair); lane loads float4 ----
__global__ __launch_bounds__(256) void wsum_kernel(const float* __restrict__ W,
                                                   float* __restrict__ WsumT) {
    int g    = blockIdx.x * 4 + (threadIdx.x >> 6);  // global wave id, 27648 total
    int lane = threadIdx.x & 63;
    int i = g / 18;          // row
    int w = g - i * 18;      // jb-pair: covers jb = 2w, 2w+1 (256 floats, 1 KB)
    const float4* p = (const float4*)(W + (size_t)i * DO + (size_t)w * 256);
    float4 v = p[lane];
    float s = (v.x + v.y) + (v.z + v.w);
    #pragma unroll
    for (int off = 16; off > 0; off >>= 1) s += __shfl_xor(s, off, 64);
    // lanes 0..31 hold block jb=2w, lanes 32..63 hold jb=2w+1
    if (lane == 0)  WsumT[(size_t)(2 * w)     * DI + i] = s;
    if (lane == 32) WsumT[(size_t)(2 * w + 1) * DI + i] = s;
}

// ---- Kernel 2: s += x * dot36(wv, G_row); G via LDS broadcast ----
__global__ __launch_bounds__(256, 4) void gated_kernel(const float* __restrict__ X,
                                                       const float* __restrict__ G,
                                                       const float* __restrict__ WsumT,
                                                       float* __restrict__ partials) {
    __shared__ float4 gs4[BPW * 72 / 4];   // 8 b x 2 ib x 36 floats = 2304 B
    __shared__ float red[4];
    float* gs = (float*)gs4;

    const int t     = threadIdx.x;
    const int w     = t >> 6;
    const int lane  = t & 63;
    const int wave0 = blockIdx.x * 4;
    const int brng  = wave0 / 24;          // block-uniform (4 | 24)
    const int a     = (wave0 % 24) >> 2;   // block's iblk quad -> ib pair {2a,2a+1}
    const int b0    = brng * BPW;
    const int iblk  = (wave0 % 24) + w;
    const int i     = iblk * 64 + lane;
    const int d     = w >> 1;              // which staged ib row this wave uses

    // Cooperative stage of G slice [b0..b0+7] x [2a..2a+1] x [0..35]:
    // contiguous 72-float runs per b -> coalesced; full MLP, one drain.
    for (int e = t; e < BPW * 72; e += 256) {
        int b = e / 72, r = e - b * 72;
        gs[e] = G[(size_t)(b0 + b) * GROW + (size_t)(2 * a) * NJ + r];
    }

    // Loop-invariant Wsum slice, coalesced: wv[k] = WsumT[k][i].
    float wv[NJ];
    #pragma unroll
    for (int k = 0; k < NJ; ++k) wv[k] = WsumT[(size_t)k * DI + i];
    #pragma unroll
    for (int k = 0; k < NJ; ++k) asm("" : "+v"(wv[k]));   // keep resident

    __syncthreads();

    const float* xp = X + (size_t)b0 * DI + i;     // coalesced, lane<->i
    float s = 0.f;
    #pragma unroll
    for (int bb = 0; bb < BPW; ++bb) {
        float x = xp[(size_t)bb * DI];
        const float4* gp = (const float4*)(gs + bb * 72 + d * 36);  // uniform addr
        float d0 = 0.f, d1 = 0.f;
        #pragma unroll
        for (int k4 = 0; k4 < 9; ++k4) {
            float4 gv = gp[k4];                    // ds_read_b128 broadcast
            d0 = fmaf(wv[4*k4+0], gv.x, d0);
            d1 = fmaf(wv[4*k4+1], gv.y, d1);
            d0 = fmaf(wv[4*k4+2], gv.z, d0);
            d1 = fmaf(wv[4*k4+3], gv.w, d1);
        }
        s = fmaf(x, d0 + d1, s);
    }

    #pragma unroll
    for (int off = 1; off < 64; off <<= 1) s += __shfl_xor(s, off, 64);
    if (lane == 0) red[w] = s;
    __syncthreads();
    if (t == 0)
        partials[blockIdx.x] = (red[0] + red[1]) + (red[2] + red[3]);
}

// ---- Kernel 3: final reduce + square (1 block) ----
__global__ __launch_bounds__(256) void finish_kernel(const float* __restrict__ partials,
                                                     float* __restrict__ out) {
    __shared__ float red[4];
    const int t = threadIdx.x;
    float s = 0.f;
    for (int e = t; e < K2_BLOCKS; e += 256) s += partials[e];
    #pragma unroll
    for (int off = 1; off < 64; off <<= 1) s += __shfl_xor(s, off, 64);
    const int w = t >> 6, lane = t & 63;
    if (lane == 0) red[w] = s;
    __syncthreads();
    if (t == 0) {
        float tot = (red[0] + red[1]) + (red[2] + red[3]);
        out[0] = tot * tot;
    }
}

extern "C" void kernel_launch(void* const* d_in, const int* in_sizes, int n_in,
                              void* d_out, int out_size, void* d_ws, size_t ws_size,
                              hipStream_t stream) {
    const float* X = (const float*)d_in[0];  // [1536,1536]
    const float* W = (const float*)d_in[1];  // [1536,4608]
    const float* G = (const float*)d_in[2];  // [1536,12,36]
    float* out = (float*)d_out;

    float* WsumT    = (float*)d_ws;                 // 55296 floats, [36][1536]
    float* partials = WsumT + (size_t)NJ * DI;      // 1152 floats

    // Kernel 1: 27648 waves = 6912 blocks x 4 waves.
    wsum_kernel<<<(DI * 18) / 4, 256, 0, stream>>>(W, WsumT);
    // Kernel 2: 1152 blocks x 256 threads -> plain partials (no atomics).
    gated_kernel<<<K2_BLOCKS, 256, 0, stream>>>(X, G, WsumT, partials);
    // Kernel 3: single block reduces 1152 partials and squares.
    finish_kernel<<<1, 256, 0, stream>>>(partials, out);
}